// Round 4
// baseline (104.086 us; speedup 1.0000x reference)
//
#include <hip/hip_runtime.h>

// DWT (Haar) forward: (16,4,1024,1024) f32 -> LL (16,4,512,512) ++ high (16,12,512,512)
//
// Memory-bound streaming kernel: 256 MiB read + 256 MiB write, zero reuse.
// R3 change: 4x work per thread (4 row-pairs spaced 128 output rows apart),
// all 16 nontemporal loads issued before compute/stores -> 16 outstanding
// 16B loads per thread to deepen MLP. Stores remain perfectly coalesced
// (1 KB contiguous per wave-instruction per subband stream).
//
// Layout:
//   in[n][c][y][x], strides (4*1024*1024, 1024*1024, 1024, 1)
//   d_out: LL flat first (16*4*512*512 = 16,777,216 floats),
//          then high[n][k][h][w], k = [LH c0..3, HL c0..3, HH c0..3],
//          strides (12*512*512, 512*512, 512, 1), base offset 16,777,216.

typedef float f32x4 __attribute__((ext_vector_type(4)));

__global__ __launch_bounds__(256) void dwt_haar_fwd(const float* __restrict__ in,
                                                    float* __restrict__ out) {
    const int t = blockIdx.x * 256 + threadIdx.x;   // [0, 2^20)

    const int w4 = t & 127;          // output col group (4 cols), 128 per row
    const int hp = (t >> 7) & 127;   // base output row in [0,128); k adds 128*k
    const int nc = t >> 14;          // plane index n*4+c, [0,64)
    const int c  = nc & 3;
    const int n  = nc >> 2;

    // ---- issue all 16 loads (4 row-pairs x 4 float4) ----
    // input rows 2*(hp+128k), 2*(hp+128k)+1 ; cols 8*w4 .. 8*w4+7
    const size_t inBase = (((size_t)nc * 1024 + 2 * hp) * 1024) + 8 * (size_t)w4;
    const f32x4* in4 = reinterpret_cast<const f32x4*>(in + inBase);

    f32x4 r0a[4], r0b[4], r1a[4], r1b[4];
#pragma unroll
    for (int k = 0; k < 4; ++k) {
        // +128 output rows = +256 input rows = +262144 floats = +65536 f32x4
        const f32x4* p = in4 + (size_t)k * 65536;
        r0a[k] = __builtin_nontemporal_load(p + 0);
        r0b[k] = __builtin_nontemporal_load(p + 1);
        r1a[k] = __builtin_nontemporal_load(p + 256);   // next input row
        r1b[k] = __builtin_nontemporal_load(p + 257);
    }

    // ---- butterflies + stores per row-pair ----
    const size_t llBase = (((size_t)nc * 512 + hp) * 512) + 4 * (size_t)w4;
    const size_t hiBase = (((size_t)(n * 12 + c) * 512 + hp) * 512) + 4 * (size_t)w4
                          + (size_t)16777216;           // high starts after LL

#pragma unroll
    for (int k = 0; k < 4; ++k) {
        f32x4 LL, LH, HL, HH;
        const f32x4 a0 = r0a[k], b0 = r0b[k], a1 = r1a[k], b1 = r1b[k];

        const float s01_0 = a0.x + a0.y, d01_0 = a0.x - a0.y;
        const float s23_0 = a1.x + a1.y, d23_0 = a1.x - a1.y;
        const float s01_1 = a0.z + a0.w, d01_1 = a0.z - a0.w;
        const float s23_1 = a1.z + a1.w, d23_1 = a1.z - a1.w;
        const float s01_2 = b0.x + b0.y, d01_2 = b0.x - b0.y;
        const float s23_2 = b1.x + b1.y, d23_2 = b1.x - b1.y;
        const float s01_3 = b0.z + b0.w, d01_3 = b0.z - b0.w;
        const float s23_3 = b1.z + b1.w, d23_3 = b1.z - b1.w;

        LL.x = (s01_0 + s23_0) * 0.5f;  LH.x = (s01_0 - s23_0) * 0.5f;
        HL.x = (d01_0 + d23_0) * 0.5f;  HH.x = (d01_0 - d23_0) * 0.5f;
        LL.y = (s01_1 + s23_1) * 0.5f;  LH.y = (s01_1 - s23_1) * 0.5f;
        HL.y = (d01_1 + d23_1) * 0.5f;  HH.y = (d01_1 - d23_1) * 0.5f;
        LL.z = (s01_2 + s23_2) * 0.5f;  LH.z = (s01_2 - s23_2) * 0.5f;
        HL.z = (d01_2 + d23_2) * 0.5f;  HH.z = (d01_2 - d23_2) * 0.5f;
        LL.w = (s01_3 + s23_3) * 0.5f;  LH.w = (s01_3 - s23_3) * 0.5f;
        HL.w = (d01_3 + d23_3) * 0.5f;  HH.w = (d01_3 - d23_3) * 0.5f;

        // +128 output rows = +65536 floats
        const size_t llOff = llBase + (size_t)k * 65536;
        const size_t hiOff = hiBase + (size_t)k * 65536;
        __builtin_nontemporal_store(LL, reinterpret_cast<f32x4*>(out + llOff));
        __builtin_nontemporal_store(LH, reinterpret_cast<f32x4*>(out + hiOff));
        __builtin_nontemporal_store(HL, reinterpret_cast<f32x4*>(out + hiOff + 1048576));
        __builtin_nontemporal_store(HH, reinterpret_cast<f32x4*>(out + hiOff + 2097152));
    }
}

extern "C" void kernel_launch(void* const* d_in, const int* in_sizes, int n_in,
                              void* d_out, int out_size, void* d_ws, size_t ws_size,
                              hipStream_t stream) {
    const float* in = (const float*)d_in[0];
    float* out = (float*)d_out;
    const int threads = 256;
    const int blocks  = (16 * 4 * 512 * 512 / 16) / threads;   // 4096
    dwt_haar_fwd<<<blocks, threads, 0, stream>>>(in, out);
}

// Round 5
// 92.121 us; speedup vs baseline: 1.1299x; 1.1299x over previous
//
#include <hip/hip_runtime.h>

// DWT (Haar) forward: (16,4,1024,1024) f32 -> LL (16,4,512,512) ++ high (16,12,512,512)
//
// Memory-bound streaming kernel: 256 MiB read + 256 MiB write, zero reuse.
// R4 change: 2 output pixels per thread so every load instruction is FULLY
// dense: lane i reads one 16B chunk at lane-stride 16B (wave = 1 KB
// contiguous per instruction, each 128B line touched exactly once).
// Stores are 8B/lane (f32x2), wave = 512B contiguous full lines per subband.
//
// Layout:
//   in[n][c][y][x], strides (4*1024*1024, 1024*1024, 1024, 1)
//   d_out: LL flat first (16*4*512*512 = 16,777,216 floats),
//          then high[n][k][h][w], k = [LH c0..3, HL c0..3, HH c0..3],
//          strides (12*512*512, 512*512, 512, 1), base offset 16,777,216.

typedef float f32x4 __attribute__((ext_vector_type(4)));
typedef float f32x2 __attribute__((ext_vector_type(2)));

__global__ __launch_bounds__(256) void dwt_haar_fwd(const float* __restrict__ in,
                                                    float* __restrict__ out) {
    const int t = blockIdx.x * 256 + threadIdx.x;   // [0, 2^23)

    const int w2 = t & 255;          // 2-output-col chunk, 256 per row
    const int h  = (t >> 8) & 511;   // output row
    const int nc = t >> 17;          // plane index n*4+c, [0,64)
    const int c  = nc & 3;
    const int n  = nc >> 2;

    // ---- input: rows 2h, 2h+1, cols 4*w2 .. 4*w2+3 (16B dense per lane) ----
    const size_t inOff = (((size_t)nc * 1024 + 2 * h) * 1024) + 4 * (size_t)w2;
    const f32x4* in4 = reinterpret_cast<const f32x4*>(in + inOff);
    const f32x4 r0 = __builtin_nontemporal_load(in4 + 0);     // row 2h
    const f32x4 r1 = __builtin_nontemporal_load(in4 + 256);   // row 2h+1

    // ---- butterfly: pixel0 = cols(2w2), pixel1 = cols(2w2+1) ----
    f32x2 LL, LH, HL, HH;
    {
        const float s01_0 = r0.x + r0.y, d01_0 = r0.x - r0.y;
        const float s23_0 = r1.x + r1.y, d23_0 = r1.x - r1.y;
        const float s01_1 = r0.z + r0.w, d01_1 = r0.z - r0.w;
        const float s23_1 = r1.z + r1.w, d23_1 = r1.z - r1.w;

        LL.x = (s01_0 + s23_0) * 0.5f;  LH.x = (s01_0 - s23_0) * 0.5f;
        HL.x = (d01_0 + d23_0) * 0.5f;  HH.x = (d01_0 - d23_0) * 0.5f;
        LL.y = (s01_1 + s23_1) * 0.5f;  LH.y = (s01_1 - s23_1) * 0.5f;
        HL.y = (d01_1 + d23_1) * 0.5f;  HH.y = (d01_1 - d23_1) * 0.5f;
    }

    // ---- output ----
    const size_t llOff = (((size_t)nc * 512 + h) * 512) + 2 * (size_t)w2;
    const size_t hiRow = (((size_t)(n * 12 + c) * 512 + h) * 512) + 2 * (size_t)w2
                         + (size_t)16777216;               // high starts after LL
    // HL +4 channels, HH +8 channels: 4*512*512 = 1,048,576 floats apart
    __builtin_nontemporal_store(LL, reinterpret_cast<f32x2*>(out + llOff));
    __builtin_nontemporal_store(LH, reinterpret_cast<f32x2*>(out + hiRow));
    __builtin_nontemporal_store(HL, reinterpret_cast<f32x2*>(out + hiRow + 1048576));
    __builtin_nontemporal_store(HH, reinterpret_cast<f32x2*>(out + hiRow + 2097152));
}

extern "C" void kernel_launch(void* const* d_in, const int* in_sizes, int n_in,
                              void* d_out, int out_size, void* d_ws, size_t ws_size,
                              hipStream_t stream) {
    const float* in = (const float*)d_in[0];
    float* out = (float*)d_out;
    const int threads = 256;
    const int blocks  = (16 * 4 * 512 * 512 / 2) / threads;   // 32768
    dwt_haar_fwd<<<blocks, threads, 0, stream>>>(in, out);
}